// Round 1
// baseline (190.835 us; speedup 1.0000x reference)
//
#include <hip/hip_runtime.h>
#include <stdint.h>

#define S_LEN 2048
#define E_DIM 1024
#define N_HEAD 16
#define HD 64
#define WIN 512

typedef __attribute__((ext_vector_type(4))) float f32x4;
typedef __attribute__((ext_vector_type(8))) short bf16x8;
typedef __attribute__((ext_vector_type(8))) unsigned short u16x8;

__device__ __forceinline__ unsigned short f2bf(float f) {
  union { float f; unsigned u; } v; v.f = f;
  unsigned r = v.u + 0x7fffu + ((v.u >> 16) & 1u);
  return (unsigned short)(r >> 16);
}

// ---------------- mask prep: normalize is_global to uint8 + per-64 block flags ----
__global__ void maskprep_kernel(const int* __restrict__ gm,
                                unsigned char* __restrict__ kmask,
                                unsigned char* __restrict__ bflag) {
  __shared__ int badw;
  int tid = threadIdx.x;
  if (tid == 0) badw = 0;
  __syncthreads();
  // If the bool array arrived byte-packed, int32 words look like 0x01010101 etc.
  for (int i = tid; i < S_LEN / 4; i += 256) {
    int v = gm[i];
    if (v != 0 && v != 1) atomicOr(&badw, 1);
  }
  __syncthreads();
  const int bytes = badw;
  const unsigned char* gb = (const unsigned char*)gm;
  for (int i = tid; i < S_LEN; i += 256)
    kmask[i] = bytes ? (unsigned char)(gb[i] != 0) : (unsigned char)(gm[i] != 0);
  if (tid < S_LEN / 64) {
    unsigned char any = 0;
    for (int j = 0; j < 64; ++j) {
      int i = tid * 64 + j;
      any |= bytes ? (unsigned char)(gb[i] != 0) : (unsigned char)(gm[i] != 0);
    }
    bflag[tid] = any;
  }
}

// ---------------- 128x128 bf16 MFMA GEMM: C = A @ W^T + bias ----------------
// MODE 0: A fp32 (convert on stage), out bf16 scattered to [H][S][HD]
// MODE 1: A bf16 (workspace),        out fp32 row-major [S][E]
template<int MODE>
__device__ __forceinline__ void gemm_body(const void* __restrict__ A_,
                                          const float* __restrict__ W,
                                          const float* __restrict__ bias,
                                          void* __restrict__ Out_) {
  __shared__ unsigned short As[128][40];
  __shared__ unsigned short Bs[128][40];
  const int tid = threadIdx.x;
  const int wid = tid >> 6, lane = tid & 63;
  const int a = lane & 15, g = lane >> 4;
  const int m0 = blockIdx.y * 128, n0 = blockIdx.x * 128;
  const int wr = (wid >> 1) * 64, wc = (wid & 1) * 64;
  const int srow = tid >> 1;          // 0..127
  const int scol = (tid & 1) * 16;    // 0 or 16
  f32x4 acc[4][4] = {};

  for (int k0 = 0; k0 < E_DIM; k0 += 32) {
    __syncthreads();
    if (MODE == 0) {
      const float* A = (const float*)A_;
      const f32x4* pa = (const f32x4*)(A + (size_t)(m0 + srow) * E_DIM + k0 + scol);
      f32x4 x0 = pa[0], x1 = pa[1], x2 = pa[2], x3 = pa[3];
      u16x8 lo, hi;
#pragma unroll
      for (int j = 0; j < 4; ++j) {
        lo[j] = f2bf(x0[j]); lo[4 + j] = f2bf(x1[j]);
        hi[j] = f2bf(x2[j]); hi[4 + j] = f2bf(x3[j]);
      }
      *(u16x8*)&As[srow][scol] = lo;
      *(u16x8*)&As[srow][scol + 8] = hi;
    } else {
      const unsigned short* A = (const unsigned short*)A_;
      const u16x8* pa = (const u16x8*)(A + (size_t)(m0 + srow) * E_DIM + k0 + scol);
      u16x8 x0 = pa[0], x1 = pa[1];
      *(u16x8*)&As[srow][scol] = x0;
      *(u16x8*)&As[srow][scol + 8] = x1;
    }
    {
      const f32x4* pb = (const f32x4*)(W + (size_t)(n0 + srow) * E_DIM + k0 + scol);
      f32x4 x0 = pb[0], x1 = pb[1], x2 = pb[2], x3 = pb[3];
      u16x8 lo, hi;
#pragma unroll
      for (int j = 0; j < 4; ++j) {
        lo[j] = f2bf(x0[j]); lo[4 + j] = f2bf(x1[j]);
        hi[j] = f2bf(x2[j]); hi[4 + j] = f2bf(x3[j]);
      }
      *(u16x8*)&Bs[srow][scol] = lo;
      *(u16x8*)&Bs[srow][scol + 8] = hi;
    }
    __syncthreads();
    bf16x8 af[4], bfv[4];
#pragma unroll
    for (int i = 0; i < 4; ++i) af[i] = *(const bf16x8*)&As[wr + i * 16 + a][g * 8];
#pragma unroll
    for (int i = 0; i < 4; ++i) bfv[i] = *(const bf16x8*)&Bs[wc + i * 16 + a][g * 8];
#pragma unroll
    for (int i = 0; i < 4; ++i)
#pragma unroll
      for (int j = 0; j < 4; ++j)
        acc[i][j] = __builtin_amdgcn_mfma_f32_16x16x32_bf16(af[i], bfv[j], acc[i][j], 0, 0, 0);
  }
  // epilogue: C/D layout col = lane&15, row = (lane>>4)*4 + r   [m89-verified]
#pragma unroll
  for (int i = 0; i < 4; ++i)
#pragma unroll
    for (int j = 0; j < 4; ++j)
#pragma unroll
      for (int r = 0; r < 4; ++r) {
        int row = m0 + wr + i * 16 + g * 4 + r;
        int col = n0 + wc + j * 16 + a;
        float v = acc[i][j][r] + bias[col];
        if (MODE == 0) {
          unsigned short* O = (unsigned short*)Out_;
          O[((size_t)(col >> 6) * S_LEN + row) * HD + (col & 63)] = f2bf(v);
        } else {
          float* O = (float*)Out_;
          O[(size_t)row * E_DIM + col] = v;
        }
      }
}

__global__ __launch_bounds__(256) void gemm_qkv_kernel(
    const float* __restrict__ q, const float* __restrict__ k, const float* __restrict__ v,
    const float* __restrict__ Wq, const float* __restrict__ Wk, const float* __restrict__ Wv,
    const float* __restrict__ bq, const float* __restrict__ bk, const float* __restrict__ bv,
    unsigned short* __restrict__ Qo, unsigned short* __restrict__ Ko, unsigned short* __restrict__ Vo) {
  int z = blockIdx.z;
  const float* A = z == 0 ? q : (z == 1 ? k : v);
  const float* W = z == 0 ? Wq : (z == 1 ? Wk : Wv);
  const float* b = z == 0 ? bq : (z == 1 ? bk : bv);
  unsigned short* O = z == 0 ? Qo : (z == 1 ? Ko : Vo);
  gemm_body<0>(A, W, b, O);
}

__global__ __launch_bounds__(256) void gemm_out_kernel(
    const unsigned short* __restrict__ Oi, const float* __restrict__ Wo,
    const float* __restrict__ bo, float* __restrict__ out) {
  gemm_body<1>(Oi, Wo, bo, out);
}

// ---------------- attention: 1 block = (head, 64 q-rows), 4 waves x 16 rows ------
__global__ __launch_bounds__(256) void attn_kernel(
    const unsigned short* __restrict__ Q, const unsigned short* __restrict__ K,
    const unsigned short* __restrict__ V, const unsigned char* __restrict__ kmask,
    const unsigned char* __restrict__ bflag, unsigned short* __restrict__ O) {
  constexpr int PADK = 72;  // rows 144B: 16B-aligned b128, banks spread (36 dw ≡ 4 mod 8)
  __shared__ unsigned short Kt[64][PADK];   // K rows [key][d]
  __shared__ unsigned short Vt[64][PADK];   // V transposed [d][key]
  __shared__ unsigned short Pl[4][16][PADK];// per-wave P staging [qrow][key]
  __shared__ unsigned int kgw[16];          // key-global flags (64 bytes)
  __shared__ int s_allk;

  const int tid = threadIdx.x;
  const int wid = tid >> 6, lane = tid & 63;
  const int a = lane & 15, g = lane >> 4;
  const int h = blockIdx.y;
  const int q0 = blockIdx.x * 64;
  const int qw = q0 + wid * 16;

  // Q A-fragments (rows = lane&15, k = 8*(lane>>4)+j contiguous)
  const size_t qbase = ((size_t)h * S_LEN + (qw + a)) * HD;
  const bf16x8 qf0 = *(const bf16x8*)(Q + qbase + g * 8);
  const bf16x8 qf1 = *(const bf16x8*)(Q + qbase + 32 + g * 8);

  int qg[4];
#pragma unroll
  for (int r = 0; r < 4; ++r) qg[r] = kmask[qw + g * 4 + r];

  if (tid < 64) {
    unsigned long long b = __ballot(kmask[q0 + tid] != 0);
    if (tid == 0) s_allk = (b != 0ull);
  }
  __syncthreads();
  const int allk = s_allk;

  float m[4], l[4];
  f32x4 acc[4];
#pragma unroll
  for (int r = 0; r < 4; ++r) { m[r] = -1e30f; l[r] = 0.f; }
#pragma unroll
  for (int d = 0; d < 4; ++d) acc[d] = f32x4{0.f, 0.f, 0.f, 0.f};

  const int srow = tid >> 2;        // key 0..63
  const int sq = (tid & 3) * 16;    // d base
  const unsigned short* Kh = K + (size_t)h * S_LEN * HD;
  const unsigned short* Vh = V + (size_t)h * S_LEN * HD;
  const unsigned char* kg = (const unsigned char*)kgw;
  const float c = 0.18033688011112042f;  // log2(e)/8  (scores/sqrt(64) in log2 domain)

  for (int kb = 0; kb < S_LEN / 64; ++kb) {
    const int k0 = kb * 64;
    bool active = allk || bflag[kb] ||
                  (k0 <= q0 + 63 + WIN && k0 + 63 >= q0 - WIN);
    if (!active) continue;  // block-uniform
    __syncthreads();
    {  // stage K row-major + V transposed, both padded
      const u16x8* pk = (const u16x8*)(Kh + (size_t)(k0 + srow) * HD + sq);
      u16x8 ka = pk[0], kb2 = pk[1];
      *(u16x8*)&Kt[srow][sq] = ka;
      *(u16x8*)&Kt[srow][sq + 8] = kb2;
      const u16x8* pv = (const u16x8*)(Vh + (size_t)(k0 + srow) * HD + sq);
      u16x8 va = pv[0], vb = pv[1];
#pragma unroll
      for (int j = 0; j < 8; ++j) Vt[sq + j][srow] = va[j];
#pragma unroll
      for (int j = 0; j < 8; ++j) Vt[sq + 8 + j][srow] = vb[j];
      if (tid < 16) kgw[tid] = ((const unsigned int*)(kmask + k0))[tid];
    }
    __syncthreads();

    // QK^T : D[16q x 16k] per ktile, contract d=64 in two MFMAs
    f32x4 s4[4];
#pragma unroll
    for (int t = 0; t < 4; ++t) {
      bf16x8 kf0 = *(const bf16x8*)&Kt[t * 16 + a][g * 8];
      bf16x8 kf1 = *(const bf16x8*)&Kt[t * 16 + a][32 + g * 8];
      f32x4 z = {0.f, 0.f, 0.f, 0.f};
      z = __builtin_amdgcn_mfma_f32_16x16x32_bf16(qf0, kf0, z, 0, 0, 0);
      z = __builtin_amdgcn_mfma_f32_16x16x32_bf16(qf1, kf1, z, 0, 0, 0);
      s4[t] = z;
    }

    // mask -> logits (log2 domain), online softmax
    float tv[4][4], pb[4][4];
#pragma unroll
    for (int t = 0; t < 4; ++t) {
      const int kc = k0 + t * 16 + a;
      const int kglob = kg[t * 16 + a];
#pragma unroll
      for (int r = 0; r < 4; ++r) {
        const int qr = qw + g * 4 + r;
        bool inc = qg[r] || kglob || ((unsigned)(qr - kc + WIN) <= (unsigned)(2 * WIN));
        tv[t][r] = inc ? s4[t][r] * c : -1e30f;
      }
    }
#pragma unroll
    for (int r = 0; r < 4; ++r) {
      float tm = fmaxf(fmaxf(tv[0][r], tv[1][r]), fmaxf(tv[2][r], tv[3][r]));
#pragma unroll
      for (int off = 1; off < 16; off <<= 1) tm = fmaxf(tm, __shfl_xor(tm, off, 16));
      const float mn = fmaxf(m[r], tm);
      const float rescale = exp2f(m[r] - mn);
      m[r] = mn;
      float ps = 0.f;
#pragma unroll
      for (int t = 0; t < 4; ++t) { float p = exp2f(tv[t][r] - mn); pb[t][r] = p; ps += p; }
#pragma unroll
      for (int off = 1; off < 16; off <<= 1) ps += __shfl_xor(ps, off, 16);
      l[r] = l[r] * rescale + ps;
#pragma unroll
      for (int d = 0; d < 4; ++d) acc[d][r] *= rescale;
    }

    // P: C-layout -> A-layout via wave-private LDS
#pragma unroll
    for (int t = 0; t < 4; ++t)
#pragma unroll
      for (int r = 0; r < 4; ++r)
        Pl[wid][g * 4 + r][t * 16 + a] = f2bf(pb[t][r]);
    bf16x8 pa0 = *(const bf16x8*)&Pl[wid][a][g * 8];
    bf16x8 pa1 = *(const bf16x8*)&Pl[wid][a][32 + g * 8];
#pragma unroll
    for (int d = 0; d < 4; ++d) {
      bf16x8 vf0 = *(const bf16x8*)&Vt[d * 16 + a][g * 8];
      bf16x8 vf1 = *(const bf16x8*)&Vt[d * 16 + a][32 + g * 8];
      acc[d] = __builtin_amdgcn_mfma_f32_16x16x32_bf16(pa0, vf0, acc[d], 0, 0, 0);
      acc[d] = __builtin_amdgcn_mfma_f32_16x16x32_bf16(pa1, vf1, acc[d], 0, 0, 0);
    }
  }

  // epilogue: O[s][h*64+d] bf16 row-major [S][E]
#pragma unroll
  for (int d = 0; d < 4; ++d)
#pragma unroll
    for (int r = 0; r < 4; ++r) {
      const int qr = qw + g * 4 + r;
      float v = acc[d][r] / l[r];
      O[(size_t)qr * E_DIM + h * HD + d * 16 + a] = f2bf(v);
    }
}

extern "C" void kernel_launch(void* const* d_in, const int* in_sizes, int n_in,
                              void* d_out, int out_size, void* d_ws, size_t ws_size,
                              hipStream_t stream) {
  const float* q  = (const float*)d_in[0];
  const float* k  = (const float*)d_in[1];
  const float* v  = (const float*)d_in[2];
  const int* isg  = (const int*)d_in[3];
  const float* Wq = (const float*)d_in[4];
  const float* bq = (const float*)d_in[5];
  const float* Wk = (const float*)d_in[6];
  const float* bk = (const float*)d_in[7];
  const float* Wv = (const float*)d_in[8];
  const float* bv = (const float*)d_in[9];
  const float* Wo = (const float*)d_in[10];
  const float* bo = (const float*)d_in[11];

  char* ws = (char*)d_ws;
  const size_t per = (size_t)N_HEAD * S_LEN * HD;  // 2M bf16 elems = 4MB
  unsigned short* Qb = (unsigned short*)ws;
  unsigned short* Kb = Qb + per;
  unsigned short* Vb = Kb + per;
  unsigned short* Ob = Vb + per;
  unsigned char* kmask = (unsigned char*)(Ob + per);
  unsigned char* bflag = kmask + S_LEN;

  maskprep_kernel<<<1, 256, 0, stream>>>(isg, kmask, bflag);
  gemm_qkv_kernel<<<dim3(E_DIM / 128, S_LEN / 128, 3), 256, 0, stream>>>(
      q, k, v, Wq, Wk, Wv, bq, bk, bv, Qb, Kb, Vb);
  attn_kernel<<<dim3(S_LEN / 64, N_HEAD), 256, 0, stream>>>(Qb, Kb, Vb, kmask, bflag, Ob);
  gemm_out_kernel<<<dim3(E_DIM / 128, S_LEN / 128), 256, 0, stream>>>(Ob, Wo, bo, (float*)d_out);
}

// Round 2
// 149.705 us; speedup vs baseline: 1.2747x; 1.2747x over previous
//
#include <hip/hip_runtime.h>
#include <stdint.h>

#define S_LEN 2048
#define E_DIM 1024
#define N_HEAD 16
#define HD 64
#define WIN 512

typedef __attribute__((ext_vector_type(4))) float f32x4;
typedef __attribute__((ext_vector_type(8))) short bf16x8;
typedef __attribute__((ext_vector_type(8))) unsigned short u16x8;

__device__ __forceinline__ unsigned short f2bf(float f) {
  union { float f; unsigned u; } v; v.f = f;
  unsigned r = v.u + 0x7fffu + ((v.u >> 16) & 1u);
  return (unsigned short)(r >> 16);
}

__device__ __forceinline__ void gl2lds16(const void* g, void* l) {
  __builtin_amdgcn_global_load_lds((const __attribute__((address_space(1))) void*)g,
                                   (__attribute__((address_space(3))) void*)l, 16, 0, 0);
}

// ---------------- fp32 -> bf16 bulk convert (q,k,v,Wq,Wk,Wv,Wo) ----------------
__global__ __launch_bounds__(256) void convert_kernel(
    const float* __restrict__ q, const float* __restrict__ k, const float* __restrict__ v,
    const float* __restrict__ wq, const float* __restrict__ wk,
    const float* __restrict__ wv, const float* __restrict__ wo,
    unsigned short* __restrict__ dst) {
  const size_t SE = (size_t)S_LEN * E_DIM, EE = (size_t)E_DIM * E_DIM;
  size_t i = ((size_t)blockIdx.x * 256 + threadIdx.x) * 8;
  const float* src;
  size_t off;
  if (i < SE) { src = q; off = i; }
  else if (i < 2 * SE) { src = k; off = i - SE; }
  else if (i < 3 * SE) { src = v; off = i - 2 * SE; }
  else if (i < 3 * SE + EE) { src = wq; off = i - 3 * SE; }
  else if (i < 3 * SE + 2 * EE) { src = wk; off = i - 3 * SE - EE; }
  else if (i < 3 * SE + 3 * EE) { src = wv; off = i - 3 * SE - 2 * EE; }
  else { src = wo; off = i - 3 * SE - 3 * EE; }
  f32x4 x0 = *(const f32x4*)(src + off);
  f32x4 x1 = *(const f32x4*)(src + off + 4);
  u16x8 o;
#pragma unroll
  for (int j = 0; j < 4; ++j) { o[j] = f2bf(x0[j]); o[4 + j] = f2bf(x1[j]); }
  *(u16x8*)(dst + i) = o;
}

// ---------------- mask prep ----------------
__global__ void maskprep_kernel(const int* __restrict__ gm,
                                unsigned char* __restrict__ kmask,
                                unsigned char* __restrict__ bflag) {
  __shared__ int badw;
  int tid = threadIdx.x;
  if (tid == 0) badw = 0;
  __syncthreads();
  for (int i = tid; i < S_LEN / 4; i += 256) {
    int v = gm[i];
    if (v != 0 && v != 1) atomicOr(&badw, 1);
  }
  __syncthreads();
  const int bytes = badw;
  const unsigned char* gb = (const unsigned char*)gm;
  for (int i = tid; i < S_LEN; i += 256)
    kmask[i] = bytes ? (unsigned char)(gb[i] != 0) : (unsigned char)(gm[i] != 0);
  if (tid < S_LEN / 64) {
    unsigned char any = 0;
    for (int j = 0; j < 64; ++j) {
      int i = tid * 64 + j;
      any |= bytes ? (unsigned char)(gb[i] != 0) : (unsigned char)(gm[i] != 0);
    }
    bflag[tid] = any;
  }
}

// ---------------- 128x128 bf16 MFMA GEMM, global_load_lds staging ----------------
// C = A @ W^T + bias.  A bf16 [M][1024], W bf16 [N][1024] (row = out col).
// OUTMODE 0: bf16 scatter [H][S][HD]; 1: fp32 row-major [S][E]; 2: bf16 [H][HD][S]
template <int OUTMODE>
__device__ __forceinline__ void gemm_body(const unsigned short* __restrict__ A,
                                          const unsigned short* __restrict__ B,
                                          const float* __restrict__ bias,
                                          void* __restrict__ Out_) {
  __shared__ unsigned short As[128][64];
  __shared__ unsigned short Bs[128][64];
  const int tid = threadIdx.x;
  const int wid = tid >> 6, lane = tid & 63;
  const int a = lane & 15, g = lane >> 4;
  const int m0 = blockIdx.y * 128, n0 = blockIdx.x * 128;
  const int wr = (wid >> 1) * 64, wc = (wid & 1) * 64;
  const int l8 = lane >> 3, l7 = (lane & 7) * 8;
  f32x4 acc[4][4] = {};

  for (int k0 = 0; k0 < E_DIM; k0 += 64) {
    __syncthreads();
#pragma unroll
    for (int c = 0; c < 4; ++c) {
      const int r0 = (wid * 4 + c) * 8;
      gl2lds16(A + (size_t)(m0 + r0 + l8) * E_DIM + k0 + l7, &As[r0][0]);
      gl2lds16(B + (size_t)(n0 + r0 + l8) * E_DIM + k0 + l7, &Bs[r0][0]);
    }
    __syncthreads();
#pragma unroll
    for (int s = 0; s < 2; ++s) {
      bf16x8 af[4], bfv[4];
#pragma unroll
      for (int i = 0; i < 4; ++i) af[i] = *(const bf16x8*)&As[wr + i * 16 + a][s * 32 + g * 8];
#pragma unroll
      for (int i = 0; i < 4; ++i) bfv[i] = *(const bf16x8*)&Bs[wc + i * 16 + a][s * 32 + g * 8];
#pragma unroll
      for (int i = 0; i < 4; ++i)
#pragma unroll
        for (int j = 0; j < 4; ++j)
          acc[i][j] = __builtin_amdgcn_mfma_f32_16x16x32_bf16(af[i], bfv[j], acc[i][j], 0, 0, 0);
    }
  }
  // C/D layout: col = lane&15, row = (lane>>4)*4 + r
#pragma unroll
  for (int i = 0; i < 4; ++i)
#pragma unroll
    for (int j = 0; j < 4; ++j)
#pragma unroll
      for (int r = 0; r < 4; ++r) {
        int row = m0 + wr + i * 16 + g * 4 + r;
        int col = n0 + wc + j * 16 + a;
        float v = acc[i][j][r] + bias[col];
        if (OUTMODE == 0) {
          unsigned short* O = (unsigned short*)Out_;
          O[((size_t)(col >> 6) * S_LEN + row) * HD + (col & 63)] = f2bf(v);
        } else if (OUTMODE == 1) {
          float* O = (float*)Out_;
          O[(size_t)row * E_DIM + col] = v;
        } else {
          unsigned short* O = (unsigned short*)Out_;  // [H][HD][S] == [col][row]
          O[(size_t)col * S_LEN + row] = f2bf(v);
        }
      }
}

__global__ __launch_bounds__(256) void gemm_qkv_kernel(
    const unsigned short* __restrict__ wsbf, const float* __restrict__ bq,
    const float* __restrict__ bk, const float* __restrict__ bv,
    unsigned short* __restrict__ Qo, unsigned short* __restrict__ Ko,
    unsigned short* __restrict__ Vo) {
  const size_t SE = (size_t)S_LEN * E_DIM, EE = (size_t)E_DIM * E_DIM;
  const int z = blockIdx.z;
  const unsigned short* A = wsbf + (size_t)z * SE;
  const unsigned short* W = wsbf + 3 * SE + (size_t)z * EE;
  const float* b = z == 0 ? bq : (z == 1 ? bk : bv);
  if (z == 2)
    gemm_body<2>(A, W, b, Vo);
  else
    gemm_body<0>(A, W, b, z == 0 ? Qo : Ko);
}

__global__ __launch_bounds__(256) void gemm_out_kernel(
    const unsigned short* __restrict__ Oi, const unsigned short* __restrict__ Wo,
    const float* __restrict__ bo, float* __restrict__ out) {
  gemm_body<1>(Oi, Wo, bo, out);
}

// ---------------- attention: block = (head, 64 q-rows), 4 waves x 16 rows, KVB=128 ----
__global__ __launch_bounds__(256) void attn_kernel(
    const unsigned short* __restrict__ Q, const unsigned short* __restrict__ K,
    const unsigned short* __restrict__ Vt_g, const unsigned char* __restrict__ kmask,
    const unsigned char* __restrict__ bflag, unsigned short* __restrict__ O) {
  constexpr int KVB = 128;
  __shared__ unsigned short Kt[128][72];    // K rows [key][d]
  __shared__ unsigned short Vt[64][136];    // V^T rows [d][key]
  __shared__ unsigned short Pl[4][16][136]; // per-wave P [qrow][key]
  __shared__ unsigned int kgw[32];
  __shared__ int s_allk;

  const int tid = threadIdx.x;
  const int wid = tid >> 6, lane = tid & 63;
  const int a = lane & 15, g = lane >> 4;
  const int h = blockIdx.y;
  const int q0 = blockIdx.x * 64;
  const int qw = q0 + wid * 16;

  const size_t qbase = ((size_t)h * S_LEN + (qw + a)) * HD;
  const bf16x8 qf0 = *(const bf16x8*)(Q + qbase + g * 8);
  const bf16x8 qf1 = *(const bf16x8*)(Q + qbase + 32 + g * 8);

  int qg[4];
#pragma unroll
  for (int r = 0; r < 4; ++r) qg[r] = kmask[qw + g * 4 + r];

  if (tid < 64) {
    unsigned long long b = __ballot(kmask[q0 + tid] != 0);
    if (tid == 0) s_allk = (b != 0ull);
  }
  __syncthreads();
  const int allk = s_allk;

  float m[4], l[4];
  f32x4 acc[4];
#pragma unroll
  for (int r = 0; r < 4; ++r) { m[r] = -1e30f; l[r] = 0.f; }
#pragma unroll
  for (int d = 0; d < 4; ++d) acc[d] = f32x4{0.f, 0.f, 0.f, 0.f};

  const unsigned short* Kh = K + (size_t)h * S_LEN * HD;
  const unsigned short* Vh = Vt_g + (size_t)h * HD * S_LEN;
  const unsigned char* kg = (const unsigned char*)kgw;
  const float c = 0.18033688011112042f;  // log2(e)/8

  for (int kb = 0; kb < S_LEN / KVB; ++kb) {
    const int k0 = kb * KVB;
    bool active = allk || bflag[2 * kb] || bflag[2 * kb + 1] ||
                  (k0 <= q0 + 63 + WIN && k0 + KVB - 1 >= q0 - WIN);
    if (!active) continue;
    __syncthreads();
    {  // stage K [128][64] and V^T [64][128], vectorized
      const u16x8* pk = (const u16x8*)(Kh + (size_t)(k0 + (tid >> 1)) * HD + (tid & 1) * 32);
      u16x8 k0v = pk[0], k1v = pk[1], k2v = pk[2], k3v = pk[3];
      u16x8* dk = (u16x8*)&Kt[tid >> 1][(tid & 1) * 32];
      dk[0] = k0v; dk[1] = k1v; dk[2] = k2v; dk[3] = k3v;
      const u16x8* pv = (const u16x8*)(Vh + (size_t)(tid >> 2) * S_LEN + k0 + (tid & 3) * 32);
      u16x8 v0 = pv[0], v1 = pv[1], v2 = pv[2], v3 = pv[3];
      u16x8* dv = (u16x8*)&Vt[tid >> 2][(tid & 3) * 32];
      dv[0] = v0; dv[1] = v1; dv[2] = v2; dv[3] = v3;
      if (tid < 32) kgw[tid] = ((const unsigned int*)(kmask + k0))[tid];
    }
    __syncthreads();

    // QK^T: 8 key-tiles of 16, contract d=64
    f32x4 s4[8];
#pragma unroll
    for (int t = 0; t < 8; ++t) {
      bf16x8 kf0 = *(const bf16x8*)&Kt[t * 16 + a][g * 8];
      bf16x8 kf1 = *(const bf16x8*)&Kt[t * 16 + a][32 + g * 8];
      f32x4 z = {0.f, 0.f, 0.f, 0.f};
      z = __builtin_amdgcn_mfma_f32_16x16x32_bf16(qf0, kf0, z, 0, 0, 0);
      z = __builtin_amdgcn_mfma_f32_16x16x32_bf16(qf1, kf1, z, 0, 0, 0);
      s4[t] = z;
    }

    float tv[8][4];
#pragma unroll
    for (int t = 0; t < 8; ++t) {
      const int kc = k0 + t * 16 + a;
      const int kglob = kg[t * 16 + a];
#pragma unroll
      for (int r = 0; r < 4; ++r) {
        const int qr = qw + g * 4 + r;
        bool inc = qg[r] || kglob || ((unsigned)(qr - kc + WIN) <= (unsigned)(2 * WIN));
        tv[t][r] = inc ? s4[t][r] * c : -3.0e38f;  // sentinel << m-init: exp2 -> exact 0
      }
    }
#pragma unroll
    for (int r = 0; r < 4; ++r) {
      float tm = tv[0][r];
#pragma unroll
      for (int t = 1; t < 8; ++t) tm = fmaxf(tm, tv[t][r]);
#pragma unroll
      for (int off = 1; off < 16; off <<= 1) tm = fmaxf(tm, __shfl_xor(tm, off, 16));
      const float mn = fmaxf(m[r], tm);
      const float rescale = exp2f(m[r] - mn);
      m[r] = mn;
      float ps = 0.f;
#pragma unroll
      for (int t = 0; t < 8; ++t) { float p = exp2f(tv[t][r] - mn); tv[t][r] = p; ps += p; }
#pragma unroll
      for (int off = 1; off < 16; off <<= 1) ps += __shfl_xor(ps, off, 16);
      l[r] = l[r] * rescale + ps;
#pragma unroll
      for (int d = 0; d < 4; ++d) acc[d][r] *= rescale;
    }

    // P: C-layout -> A-layout via wave-private LDS
#pragma unroll
    for (int t = 0; t < 8; ++t)
#pragma unroll
      for (int r = 0; r < 4; ++r)
        Pl[wid][g * 4 + r][t * 16 + a] = f2bf(tv[t][r]);
    bf16x8 pa[4];
#pragma unroll
    for (int ks = 0; ks < 4; ++ks) pa[ks] = *(const bf16x8*)&Pl[wid][a][ks * 32 + g * 8];
#pragma unroll
    for (int d = 0; d < 4; ++d) {
#pragma unroll
      for (int ks = 0; ks < 4; ++ks) {
        bf16x8 vf = *(const bf16x8*)&Vt[d * 16 + a][ks * 32 + g * 8];
        acc[d] = __builtin_amdgcn_mfma_f32_16x16x32_bf16(pa[ks], vf, acc[d], 0, 0, 0);
      }
    }
  }

#pragma unroll
  for (int d = 0; d < 4; ++d)
#pragma unroll
    for (int r = 0; r < 4; ++r) {
      const int qr = qw + g * 4 + r;
      float v = acc[d][r] / l[r];
      O[(size_t)qr * E_DIM + h * HD + d * 16 + a] = f2bf(v);
    }
}

extern "C" void kernel_launch(void* const* d_in, const int* in_sizes, int n_in,
                              void* d_out, int out_size, void* d_ws, size_t ws_size,
                              hipStream_t stream) {
  const float* q  = (const float*)d_in[0];
  const float* k  = (const float*)d_in[1];
  const float* v  = (const float*)d_in[2];
  const int* isg  = (const int*)d_in[3];
  const float* bq = (const float*)d_in[5];
  const float* bk = (const float*)d_in[7];
  const float* bv = (const float*)d_in[9];
  const float* bo = (const float*)d_in[11];
  const float* Wq = (const float*)d_in[4];
  const float* Wk = (const float*)d_in[6];
  const float* Wv = (const float*)d_in[8];
  const float* Wo = (const float*)d_in[10];

  const size_t SE = (size_t)S_LEN * E_DIM, EE = (size_t)E_DIM * E_DIM;
  unsigned short* wsbf = (unsigned short*)d_ws;   // [q|k|v|Wq|Wk|Wv|Wo] bf16
  unsigned short* Qb = wsbf + 3 * SE + 4 * EE;    // [H][S][HD]
  unsigned short* Kb = Qb + SE;                   // [H][S][HD]
  unsigned short* Vb = Kb + SE;                   // [H][HD][S] (transposed)
  unsigned short* Ob = wsbf;                      // alias q-bf16 (dead after qkv GEMM)
  unsigned char* kmask = (unsigned char*)(Vb + SE);
  unsigned char* bflag = kmask + S_LEN;

  const int total_conv_blocks = (int)((3 * SE + 4 * EE) / (256 * 8));
  convert_kernel<<<total_conv_blocks, 256, 0, stream>>>(q, k, v, Wq, Wk, Wv, Wo, wsbf);
  maskprep_kernel<<<1, 256, 0, stream>>>(isg, kmask, bflag);
  gemm_qkv_kernel<<<dim3(E_DIM / 128, S_LEN / 128, 3), 256, 0, stream>>>(
      wsbf, bq, bk, bv, Qb, Kb, Vb);
  attn_kernel<<<dim3(S_LEN / 64, N_HEAD), 256, 0, stream>>>(Qb, Kb, Vb, kmask, bflag, Ob);
  gemm_out_kernel<<<dim3(E_DIM / 128, S_LEN / 128), 256, 0, stream>>>(
      Ob, wsbf + 3 * SE + 3 * EE, bo, (float*)d_out);
}

// Round 3
// 127.510 us; speedup vs baseline: 1.4966x; 1.1741x over previous
//
#include <hip/hip_runtime.h>
#include <hip/hip_bf16.h>
#include <stdint.h>

#define S_LEN 2048
#define E_DIM 1024
#define N_HEAD 16
#define HD 64
#define WIN 512

typedef __attribute__((ext_vector_type(4))) float f32x4;
typedef __attribute__((ext_vector_type(8))) short bf16x8;
typedef __attribute__((ext_vector_type(8))) unsigned short u16x8;

__device__ __forceinline__ unsigned f2bf2(float lo, float hi) {
  __hip_bfloat162 h = __float22bfloat162_rn(make_float2(lo, hi));
  return *reinterpret_cast<unsigned*>(&h);
}
__device__ __forceinline__ unsigned short f2bf(float f) {
  __hip_bfloat16 h = __float2bfloat16(f);
  return *reinterpret_cast<unsigned short*>(&h);
}

__device__ __forceinline__ void gl2lds16(const void* g, void* l) {
  __builtin_amdgcn_global_load_lds((const __attribute__((address_space(1))) void*)g,
                                   (__attribute__((address_space(3))) void*)l, 16, 0, 0);
}

// ---------------- fp32 -> bf16 bulk convert (q,k,v,Wq,Wk,Wv,Wo) ----------------
__global__ __launch_bounds__(256) void convert_kernel(
    const float* __restrict__ q, const float* __restrict__ k, const float* __restrict__ v,
    const float* __restrict__ wq, const float* __restrict__ wk,
    const float* __restrict__ wv, const float* __restrict__ wo,
    unsigned short* __restrict__ dst) {
  const size_t SE = (size_t)S_LEN * E_DIM, EE = (size_t)E_DIM * E_DIM;
  size_t i = ((size_t)blockIdx.x * 256 + threadIdx.x) * 8;
  const float* src;
  size_t off;
  if (i < SE) { src = q; off = i; }
  else if (i < 2 * SE) { src = k; off = i - SE; }
  else if (i < 3 * SE) { src = v; off = i - 2 * SE; }
  else if (i < 3 * SE + EE) { src = wq; off = i - 3 * SE; }
  else if (i < 3 * SE + 2 * EE) { src = wk; off = i - 3 * SE - EE; }
  else if (i < 3 * SE + 3 * EE) { src = wv; off = i - 3 * SE - 2 * EE; }
  else { src = wo; off = i - 3 * SE - 3 * EE; }
  f32x4 x0 = *(const f32x4*)(src + off);
  f32x4 x1 = *(const f32x4*)(src + off + 4);
  union { u16x8 v; unsigned u[4]; } o;
  o.u[0] = f2bf2(x0[0], x0[1]); o.u[1] = f2bf2(x0[2], x0[3]);
  o.u[2] = f2bf2(x1[0], x1[1]); o.u[3] = f2bf2(x1[2], x1[3]);
  *(u16x8*)(dst + i) = o.v;
}

// ---------------- mask prep ----------------
__global__ void maskprep_kernel(const int* __restrict__ gm,
                                unsigned char* __restrict__ kmask,
                                unsigned char* __restrict__ bflag) {
  __shared__ int badw;
  int tid = threadIdx.x;
  if (tid == 0) badw = 0;
  __syncthreads();
  for (int i = tid; i < S_LEN / 4; i += 256) {
    int v = gm[i];
    if (v != 0 && v != 1) atomicOr(&badw, 1);
  }
  __syncthreads();
  const int bytes = badw;
  const unsigned char* gb = (const unsigned char*)gm;
  for (int i = tid; i < S_LEN; i += 256)
    kmask[i] = bytes ? (unsigned char)(gb[i] != 0) : (unsigned char)(gm[i] != 0);
  if (tid < S_LEN / 64) {
    unsigned char any = 0;
    for (int j = 0; j < 64; ++j) {
      int i = tid * 64 + j;
      any |= bytes ? (unsigned char)(gb[i] != 0) : (unsigned char)(gm[i] != 0);
    }
    bflag[tid] = any;
  }
}

// ---------------- 64xBN bf16 MFMA GEMM, global_load_lds staging ----------------
// C = A @ W^T + bias. OUTMODE 0: bf16 [H][S][HD]; 1: fp32 [S][E]; 2: bf16 [H][HD][S]
template <int BN, int OUTMODE>
__device__ __forceinline__ void gemm_body(const unsigned short* __restrict__ A,
                                          const unsigned short* __restrict__ B,
                                          const float* __restrict__ bias,
                                          void* __restrict__ Out_) {
  __shared__ unsigned short As[64][64];
  __shared__ unsigned short Bs[BN][64];
  constexpr int MI = (BN == 128) ? 2 : 1;
  const int tid = threadIdx.x;
  const int wid = tid >> 6, lane = tid & 63;
  const int a = lane & 15, g = lane >> 4;
  const int m0 = blockIdx.y * 64, n0 = blockIdx.x * BN;
  const int wr = (BN == 128) ? (wid >> 1) * 32 : wid * 16;
  const int wc = (BN == 128) ? (wid & 1) * 64 : 0;
  const int l8 = lane >> 3, l7 = (lane & 7) * 8;
  f32x4 acc[MI][4] = {};

  for (int k0 = 0; k0 < E_DIM; k0 += 64) {
    __syncthreads();
#pragma unroll
    for (int c = 0; c < 2; ++c) {
      const int r0 = (wid * 2 + c) * 8;
      gl2lds16(A + (size_t)(m0 + r0 + l8) * E_DIM + k0 + l7, &As[r0][0]);
    }
#pragma unroll
    for (int c = 0; c < BN / 32; ++c) {
      const int r0 = (wid * (BN / 32) + c) * 8;
      gl2lds16(B + (size_t)(n0 + r0 + l8) * E_DIM + k0 + l7, &Bs[r0][0]);
    }
    __syncthreads();
#pragma unroll
    for (int s = 0; s < 2; ++s) {
      bf16x8 af[MI], bfv[4];
#pragma unroll
      for (int i = 0; i < MI; ++i) af[i] = *(const bf16x8*)&As[wr + i * 16 + a][s * 32 + g * 8];
#pragma unroll
      for (int j = 0; j < 4; ++j) bfv[j] = *(const bf16x8*)&Bs[wc + j * 16 + a][s * 32 + g * 8];
#pragma unroll
      for (int i = 0; i < MI; ++i)
#pragma unroll
        for (int j = 0; j < 4; ++j)
          acc[i][j] = __builtin_amdgcn_mfma_f32_16x16x32_bf16(af[i], bfv[j], acc[i][j], 0, 0, 0);
    }
  }
  // C/D layout: col = lane&15, row = (lane>>4)*4 + r
#pragma unroll
  for (int i = 0; i < MI; ++i)
#pragma unroll
    for (int j = 0; j < 4; ++j) {
      const int row0 = m0 + wr + i * 16 + g * 4;
      const int col = n0 + wc + j * 16 + a;
      if (OUTMODE == 2) {
        unsigned short* O = (unsigned short*)Out_;  // [H][HD][S] == [col][row]
        unsigned lo = f2bf2(acc[i][j][0] + bias[col], acc[i][j][1] + bias[col]);
        unsigned hi = f2bf2(acc[i][j][2] + bias[col], acc[i][j][3] + bias[col]);
        uint2 pk; pk.x = lo; pk.y = hi;
        *(uint2*)&O[(size_t)col * S_LEN + row0] = pk;
      } else {
#pragma unroll
        for (int r = 0; r < 4; ++r) {
          float v = acc[i][j][r] + bias[col];
          if (OUTMODE == 0) {
            unsigned short* O = (unsigned short*)Out_;
            O[((size_t)(col >> 6) * S_LEN + row0 + r) * HD + (col & 63)] = f2bf(v);
          } else {
            float* O = (float*)Out_;
            O[(size_t)(row0 + r) * E_DIM + col] = v;
          }
        }
      }
    }
}

__global__ __launch_bounds__(256) void gemm_qkv_kernel(
    const unsigned short* __restrict__ wsbf, const float* __restrict__ bq,
    const float* __restrict__ bk, const float* __restrict__ bv,
    unsigned short* __restrict__ Qo, unsigned short* __restrict__ Ko,
    unsigned short* __restrict__ Vo) {
  const size_t SE = (size_t)S_LEN * E_DIM, EE = (size_t)E_DIM * E_DIM;
  const int z = blockIdx.z;
  const unsigned short* A = wsbf + (size_t)z * SE;
  const unsigned short* W = wsbf + 3 * SE + (size_t)z * EE;
  const float* b = z == 0 ? bq : (z == 1 ? bk : bv);
  if (z == 2)
    gemm_body<128, 2>(A, W, b, Vo);
  else
    gemm_body<128, 0>(A, W, b, z == 0 ? Qo : Ko);
}

__global__ __launch_bounds__(256) void gemm_out_kernel(
    const unsigned short* __restrict__ Oi, const unsigned short* __restrict__ Wo,
    const float* __restrict__ bo, float* __restrict__ out) {
  gemm_body<64, 1>(Oi, Wo, bo, out);
}

// ---------------- attention: block = (head, 64 q-rows), 4 waves x 16 rows, KVB=128 ----
__global__ __launch_bounds__(256) void attn_kernel(
    const unsigned short* __restrict__ Q, const unsigned short* __restrict__ K,
    const unsigned short* __restrict__ Vt_g, const unsigned char* __restrict__ kmask,
    const unsigned char* __restrict__ bflag, unsigned short* __restrict__ O) {
  __shared__ unsigned short Kt[128][72];   // K rows [key][d], padded
  __shared__ unsigned short Vt[64][136];   // V^T rows [d][key], padded
  __shared__ float Plf[4][16][132];        // per-wave P (f32) [qrow][key], conflict-free
  __shared__ unsigned char kmAll[S_LEN];
  __shared__ int s_allk;

  const int tid = threadIdx.x;
  const int wid = tid >> 6, lane = tid & 63;
  const int a = lane & 15, g = lane >> 4;
  const int h = blockIdx.y;
  const int q0 = blockIdx.x * 64;
  const int qw = q0 + wid * 16;

  ((uint2*)kmAll)[tid] = ((const uint2*)kmask)[tid];
  if (tid < 64) {
    unsigned long long b = __ballot(kmask[q0 + tid] != 0);
    if (tid == 0) s_allk = (b != 0ull);
  }

  const size_t qbase = ((size_t)h * S_LEN + (qw + a)) * HD;
  const bf16x8 qf0 = *(const bf16x8*)(Q + qbase + g * 8);
  const bf16x8 qf1 = *(const bf16x8*)(Q + qbase + 32 + g * 8);

  __syncthreads();
  const int allk = s_allk;
  int qg[4];
#pragma unroll
  for (int r = 0; r < 4; ++r) qg[r] = kmAll[qw + g * 4 + r];

  // uniform active-tile mask (16 tiles of 128 keys)
  unsigned amask = 0;
  int lo = (q0 - WIN) >> 7; if (lo < 0) lo = 0;
  int hi = (q0 + 63 + WIN) >> 7; if (hi > 15) hi = 15;
#pragma unroll
  for (int t2 = 0; t2 < 16; ++t2) {
    bool act = allk || (t2 >= lo && t2 <= hi) || bflag[2 * t2] || bflag[2 * t2 + 1];
    amask |= (unsigned)act << t2;
  }

  float m[4], l[4];
  f32x4 acc[4];
#pragma unroll
  for (int r = 0; r < 4; ++r) { m[r] = -1e30f; l[r] = 0.f; }
#pragma unroll
  for (int d = 0; d < 4; ++d) acc[d] = f32x4{0.f, 0.f, 0.f, 0.f};

  const unsigned short* Kh = K + (size_t)h * S_LEN * HD;
  const unsigned short* Vh = Vt_g + (size_t)h * HD * S_LEN;
  const float c = 0.18033688011112042f;  // log2(e)/8

  u16x8 kreg[4], vreg[4];
  auto issue = [&](int k0) {
    const u16x8* pk = (const u16x8*)(Kh + (size_t)(k0 + (tid >> 1)) * HD + (tid & 1) * 32);
    kreg[0] = pk[0]; kreg[1] = pk[1]; kreg[2] = pk[2]; kreg[3] = pk[3];
    const u16x8* pv = (const u16x8*)(Vh + (size_t)(tid >> 2) * S_LEN + k0 + (tid & 3) * 32);
    vreg[0] = pv[0]; vreg[1] = pv[1]; vreg[2] = pv[2]; vreg[3] = pv[3];
  };

  int kb = __builtin_ctz(amask);
  issue(kb * 128);
  while (kb < 16) {
    const unsigned rem = amask >> (kb + 1);
    const int nxt = rem ? kb + 1 + __builtin_ctz(rem) : 16;
    const int k0 = kb * 128;

    __syncthreads();  // prior tile's LDS reads complete
    {
      u16x8* dk = (u16x8*)&Kt[tid >> 1][(tid & 1) * 32];
      dk[0] = kreg[0]; dk[1] = kreg[1]; dk[2] = kreg[2]; dk[3] = kreg[3];
      u16x8* dv = (u16x8*)&Vt[tid >> 2][(tid & 3) * 32];
      dv[0] = vreg[0]; dv[1] = vreg[1]; dv[2] = vreg[2]; dv[3] = vreg[3];
    }
    __syncthreads();
    if (nxt < 16) issue(nxt * 128);  // overlap next tile's HBM latency with compute

    // ---- QK^T ----
    f32x4 s4[8];
    __builtin_amdgcn_s_setprio(1);
#pragma unroll
    for (int t = 0; t < 8; ++t) {
      bf16x8 kf0 = *(const bf16x8*)&Kt[t * 16 + a][g * 8];
      bf16x8 kf1 = *(const bf16x8*)&Kt[t * 16 + a][32 + g * 8];
      f32x4 z = {0.f, 0.f, 0.f, 0.f};
      z = __builtin_amdgcn_mfma_f32_16x16x32_bf16(qf0, kf0, z, 0, 0, 0);
      z = __builtin_amdgcn_mfma_f32_16x16x32_bf16(qf1, kf1, z, 0, 0, 0);
      s4[t] = z;
    }
    __builtin_amdgcn_s_setprio(0);

    // ---- mask -> logits ----
    float tv[8][4];
    const bool interior = (k0 >= q0 - 449) && (k0 <= q0 + 385);  // all rows fully windowed
    if (interior) {
#pragma unroll
      for (int t = 0; t < 8; ++t)
#pragma unroll
        for (int r = 0; r < 4; ++r) tv[t][r] = s4[t][r] * c;
    } else {
#pragma unroll
      for (int t = 0; t < 8; ++t) {
        const int kc = k0 + t * 16 + a;
        const int kglob = kmAll[kc];
#pragma unroll
        for (int r = 0; r < 4; ++r) {
          const int qr = qw + g * 4 + r;
          bool inc = qg[r] || kglob || ((unsigned)(qr - kc + WIN) <= (unsigned)(2 * WIN));
          tv[t][r] = inc ? s4[t][r] * c : -3.0e38f;
        }
      }
    }

    // ---- online softmax ----
#pragma unroll
    for (int r = 0; r < 4; ++r) {
      float tm = fmaxf(fmaxf(tv[0][r], tv[1][r]), fmaxf(tv[2][r], tv[3][r]));
      tm = fmaxf(tm, fmaxf(fmaxf(tv[4][r], tv[5][r]), fmaxf(tv[6][r], tv[7][r])));
#pragma unroll
      for (int off = 1; off < 16; off <<= 1) tm = fmaxf(tm, __shfl_xor(tm, off, 16));
      const float mn = fmaxf(m[r], tm);
      const float rs = __builtin_amdgcn_exp2f(m[r] - mn);
      m[r] = mn;
      float ps = 0.f;
#pragma unroll
      for (int t = 0; t < 8; ++t) {
        float p = __builtin_amdgcn_exp2f(tv[t][r] - mn);
        tv[t][r] = p; ps += p;
      }
#pragma unroll
      for (int off = 1; off < 16; off <<= 1) ps += __shfl_xor(ps, off, 16);
      l[r] = l[r] * rs + ps;
#pragma unroll
      for (int d = 0; d < 4; ++d) acc[d][r] *= rs;
    }

    // ---- P transpose via wave-private f32 LDS (conflict-free) ----
#pragma unroll
    for (int t = 0; t < 8; ++t)
#pragma unroll
      for (int r = 0; r < 4; ++r)
        Plf[wid][g * 4 + r][t * 16 + a] = tv[t][r];
    bf16x8 pa[4];
#pragma unroll
    for (int ks = 0; ks < 4; ++ks) {
      const float* pp = &Plf[wid][a][ks * 32 + g * 8];
      f32x4 x0 = *(const f32x4*)pp, x1 = *(const f32x4*)(pp + 4);
      union { bf16x8 v; unsigned u[4]; } pu;
      pu.u[0] = f2bf2(x0[0], x0[1]); pu.u[1] = f2bf2(x0[2], x0[3]);
      pu.u[2] = f2bf2(x1[0], x1[1]); pu.u[3] = f2bf2(x1[2], x1[3]);
      pa[ks] = pu.v;
    }

    // ---- PV ----
    __builtin_amdgcn_s_setprio(1);
#pragma unroll
    for (int d = 0; d < 4; ++d)
#pragma unroll
      for (int ks = 0; ks < 4; ++ks) {
        bf16x8 vf = *(const bf16x8*)&Vt[d * 16 + a][ks * 32 + g * 8];
        acc[d] = __builtin_amdgcn_mfma_f32_16x16x32_bf16(pa[ks], vf, acc[d], 0, 0, 0);
      }
    __builtin_amdgcn_s_setprio(0);
    kb = nxt;
  }

#pragma unroll
  for (int d = 0; d < 4; ++d)
#pragma unroll
    for (int r = 0; r < 4; ++r) {
      const int qr = qw + g * 4 + r;
      float v = acc[d][r] / l[r];
      O[(size_t)qr * E_DIM + h * HD + d * 16 + a] = f2bf(v);
    }
}

extern "C" void kernel_launch(void* const* d_in, const int* in_sizes, int n_in,
                              void* d_out, int out_size, void* d_ws, size_t ws_size,
                              hipStream_t stream) {
  const float* q  = (const float*)d_in[0];
  const float* k  = (const float*)d_in[1];
  const float* v  = (const float*)d_in[2];
  const int* isg  = (const int*)d_in[3];
  const float* Wq = (const float*)d_in[4];
  const float* bq = (const float*)d_in[5];
  const float* Wk = (const float*)d_in[6];
  const float* bk = (const float*)d_in[7];
  const float* Wv = (const float*)d_in[8];
  const float* bv = (const float*)d_in[9];
  const float* Wo = (const float*)d_in[10];
  const float* bo = (const float*)d_in[11];

  const size_t SE = (size_t)S_LEN * E_DIM, EE = (size_t)E_DIM * E_DIM;
  unsigned short* wsbf = (unsigned short*)d_ws;   // [q|k|v|Wq|Wk|Wv|Wo] bf16
  unsigned short* Qb = wsbf + 3 * SE + 4 * EE;    // [H][S][HD]
  unsigned short* Kb = Qb + SE;                   // [H][S][HD]
  unsigned short* Vb = Kb + SE;                   // [H][HD][S] (transposed)
  unsigned short* Ob = wsbf;                      // alias q-bf16 (dead after qkv GEMM)
  unsigned char* kmask = (unsigned char*)(Vb + SE);
  unsigned char* bflag = kmask + S_LEN;

  const int total_conv_blocks = (int)((3 * SE + 4 * EE) / (256 * 8));
  convert_kernel<<<total_conv_blocks, 256, 0, stream>>>(q, k, v, Wq, Wk, Wv, Wo, wsbf);
  maskprep_kernel<<<1, 256, 0, stream>>>(isg, kmask, bflag);
  gemm_qkv_kernel<<<dim3(E_DIM / 128, S_LEN / 64, 3), 256, 0, stream>>>(
      wsbf, bq, bk, bv, Qb, Kb, Vb);
  attn_kernel<<<dim3(S_LEN / 64, N_HEAD), 256, 0, stream>>>(Qb, Kb, Vb, kmask, bflag, Ob);
  gemm_out_kernel<<<dim3(E_DIM / 64, S_LEN / 64), 256, 0, stream>>>(
      Ob, wsbf + 3 * SE + 3 * EE, bo, (float*)d_out);
}